// Round 5
// baseline (6813.138 us; speedup 1.0000x reference)
//
#include <hip/hip_runtime.h>

typedef unsigned short u16;
typedef unsigned int u32;
typedef __attribute__((ext_vector_type(8))) short short8;
typedef __attribute__((ext_vector_type(4))) float f32x4;

#define DEV __device__ __forceinline__
#define SB0() __builtin_amdgcn_sched_barrier(0)

DEV u16 f2bf(float f){
  u32 u = __builtin_bit_cast(u32, f);
  u += 0x7fffu + ((u >> 16) & 1u);
  return (u16)(u >> 16);
}
DEV float sigm(float x){ return 1.f / (1.f + __expf(-x)); }
DEV float tanh_(float x){ return 2.f / (1.f + __expf(-2.f * x)) - 1.f; }

DEV void gl_lds16(const void* g, void* l){
  __builtin_amdgcn_global_load_lds(
      (const __attribute__((address_space(1))) u32*)g,
      (__attribute__((address_space(3))) u32*)l, 16, 0, 0);
}

#define MFMA16(A,B,C) __builtin_amdgcn_mfma_f32_16x16x32_bf16(A, B, C, 0, 0, 0)

// ---------------- weight pack ----------------
__global__ void pack_w_kernel(const float* __restrict__ wi, const float* __restrict__ wh,
                              u16* __restrict__ dst, int Ki, int Kh, int nrows){
  const int KT = Ki + Kh;
  const long n = (long)nrows * KT;
  for (long idx = (long)blockIdx.x * blockDim.x + threadIdx.x; idx < n;
       idx += (long)gridDim.x * blockDim.x){
    int r = (int)(idx / KT), c = (int)(idx % KT);
    float v = (c < Ki) ? wi[(long)r * Ki + c] : wh[(long)r * Kh + (c - Ki)];
    dst[idx] = f2bf(v);
  }
}

// ---------------- h0 init ----------------
struct InitA { const float* z8; const float* wini; const float* bini; float* h0f; u16* h0bf; };

__global__ __launch_bounds__(256)
void init_kernel(InitA A0, InitA A1){
  const InitA& a = (blockIdx.z == 0) ? A0 : A1;
  __shared__ float lz[64][128];
  const int tid = threadIdx.x;
  const int rb = blockIdx.x * 64, ub = blockIdx.y * 128;
  {
    const int row = tid >> 2, q = tid & 3;
    const float4* p = (const float4*)(a.z8 + (long)(rb + row) * 128 + q * 32);
    float4* dst = (float4*)&lz[row][q * 32];
    #pragma unroll
    for (int j = 0; j < 8; ++j) dst[j] = p[j];
  }
  __syncthreads();
  const int u = ub + (tid & 127);
  const int rg = tid >> 7;
  float acc[32];
  #pragma unroll
  for (int r = 0; r < 32; ++r) acc[r] = 0.f;
  for (int k = 0; k < 128; k += 4){
    float4 w4 = *(const float4*)&a.wini[(long)u * 128 + k];
    #pragma unroll
    for (int r = 0; r < 32; ++r){
      float4 z4 = *(const float4*)&lz[rg * 32 + r][k];
      acc[r] += w4.x * z4.x + w4.y * z4.y + w4.z * z4.z + w4.w * z4.w;
    }
  }
  const float b = a.bini[u];
  #pragma unroll
  for (int r = 0; r < 32; ++r){
    const long row = rb + rg * 32 + r;
    const float v = acc[r] + b;
    a.h0f[row * 1024 + u] = v;
    a.h0bf[row * 1024 + u] = f2bf(v);
  }
}

// ---------------- fused GRU cell GEMM (256x192 tile, per-gate phased pipeline) ----
struct CellA {
  const u16* W;                 // [3072][KTOT] bf16 packed
  const float* bi; const float* bh;   // [3072]
  const float* afz; const float* afo; // cell1 f32 A region (z slice / prev out)
  const u16* ab1; const u16* ab2;     // bf16 A regions, row stride 1024
  const float* holdr; float* holdw; u16* hbfw;
};

template<int CELL>
__global__ __attribute__((amdgpu_waves_per_eu(2, 2))) __launch_bounds__(512)
void cell_kernel(CellA A0, CellA A1, const int* dn1, int step){
  constexpr int KTOT = (CELL == 1) ? 1152 : 2048;
  constexpr int KT = KTOT / 64;
  constexpr int NI_STEPS = (CELL == 1) ? 2 : 16;   // kt < NI_STEPS -> input-part of n-gate

  __shared__ u16 lA[2][256 * 64];
  __shared__ u16 lB[2][192 * 64];

  const CellA& a = (blockIdx.y == 0) ? A0 : A1;
  const int tid = threadIdx.x;
  const int lane = tid & 63;
  const int wv = tid >> 6;      // 0..7
  const int wm = wv >> 1;       // 0..3  (64-row group)
  const int wn = wv & 1;        // 0..1  (32-unit group)
  const int bid = blockIdx.x;
  const int m_idx = (bid >> 3) & 7;
  const int n_idx = ((bid & 7) << 1) | (bid >> 6);   // XCD-grouped N-strips
  const int brow = m_idx * 256;
  const int u0 = n_idx * 64;

  f32x4 aR[4][2] = {}; f32x4 aZ[4][2] = {};
  f32x4 aNI[4][2] = {}; f32x4 aNH[4][2] = {};

  const int srow = tid >> 3;                       // 0..63
  const int sxor8 = ((tid & 7) ^ (srow & 7)) * 8;  // pre-swizzled source slot (x8 u16)

  auto stage = [&](int bf, int kt){                // 7 gl_lds16 per thread per tile
    const int k0 = kt * 64;
    const u16* ab; int kk;
    if constexpr (CELL == 1){ ab = a.ab1; kk = k0 - 128; }
    else { if (k0 < 1024){ ab = a.ab1; kk = k0; } else { ab = a.ab2; kk = k0 - 1024; } }
    #pragma unroll
    for (int j = 0; j < 4; ++j)
      gl_lds16(ab + (long)(brow + j * 64 + srow) * 1024 + kk + sxor8,
               &lA[bf][(j * 64 + wv * 8) * 64]);
    #pragma unroll
    for (int g = 0; g < 3; ++g)
      gl_lds16(a.W + (long)(g * 1024 + u0 + srow) * KTOT + k0 + sxor8,
               &lB[bf][(g * 64 + wv * 8) * 64]);
  };

  const int l15 = lane & 15;
  const int kq = lane >> 4;
  const int sx = lane & 7;

  auto read_a = [&](int bf, short8 (&af)[2][4]){
    #pragma unroll
    for (int ks = 0; ks < 2; ++ks){
      const int soff = (((ks * 4 + kq) ^ sx)) * 8;
      #pragma unroll
      for (int fr = 0; fr < 4; ++fr)
        af[ks][fr] = *(const short8*)&lA[bf][(wm * 64 + fr * 16 + l15) * 64 + soff];
    }
  };
  auto read_b = [&](int bf, int g, short8 (&bg)[2][2]){
    #pragma unroll
    for (int ks = 0; ks < 2; ++ks){
      const int soff = (((ks * 4 + kq) ^ sx)) * 8;
      #pragma unroll
      for (int fc = 0; fc < 2; ++fc)
        bg[ks][fc] = *(const short8*)&lB[bf][(g * 64 + wn * 32 + fc * 16 + l15) * 64 + soff];
    }
  };
  auto mfma_gate = [&](const short8 (&af)[2][4], const short8 (&bg)[2][2], f32x4 (&A)[4][2]){
    #pragma unroll
    for (int ks = 0; ks < 2; ++ks)
      #pragma unroll
      for (int fr = 0; fr < 4; ++fr)
        #pragma unroll
        for (int fc = 0; fc < 2; ++fc)
          A[fr][fc] = MFMA16(af[ks][fr], bg[ks][fc], A[fr][fc]);
  };

  int kstart;
  if constexpr (CELL == 1){
    // ---- phase A: f32 input block (K=0..127), un-pipelined (one-off) ----
    const int n1v = *dn1;
    const float* fsrc; long fstr;
    if (step < n1v){ fsrc = a.afz; fstr = 64 * 128; }
    else           { fsrc = a.afo; fstr = 128; }
    {
      const int row = tid >> 1, half = tid & 1;
      #pragma unroll
      for (int st = 0; st < 2; ++st){
        const float* pp = fsrc + (long)(brow + row) * fstr + st * 64 + half * 32;
        #pragma unroll
        for (int q = 0; q < 4; ++q){
          float4 x = ((const float4*)pp)[2 * q];
          float4 y = ((const float4*)pp)[2 * q + 1];
          short8 o;
          o[0] = (short)f2bf(x.x); o[1] = (short)f2bf(x.y);
          o[2] = (short)f2bf(x.z); o[3] = (short)f2bf(x.w);
          o[4] = (short)f2bf(y.x); o[5] = (short)f2bf(y.y);
          o[6] = (short)f2bf(y.z); o[7] = (short)f2bf(y.w);
          const int s = half * 4 + q;
          *(short8*)&lA[st][row * 64 + ((s ^ (row & 7)) * 8)] = o;
        }
        #pragma unroll
        for (int g = 0; g < 3; ++g)
          gl_lds16(a.W + (long)(g * 1024 + u0 + srow) * KTOT + st * 64 + sxor8,
                   &lB[st][(g * 64 + wv * 8) * 64]);
      }
    }
    __syncthreads();                       // full drain ok (one-time)
    #pragma unroll
    for (int st = 0; st < 2; ++st){
      short8 af[2][4], bg[2][2];
      read_a(st, af);
      read_b(st, 0, bg);
      asm volatile("s_waitcnt lgkmcnt(0)" ::: "memory"); SB0();
      mfma_gate(af, bg, aR);
      read_b(st, 1, bg);
      asm volatile("s_waitcnt lgkmcnt(0)" ::: "memory"); SB0();
      mfma_gate(af, bg, aZ);
      read_b(st, 2, bg);
      asm volatile("s_waitcnt lgkmcnt(0)" ::: "memory"); SB0();
      mfma_gate(af, bg, aNI);
    }
    __syncthreads();                       // all reads done -> buffers free
    stage(0, 2); stage(1, 3);
    kstart = 2;
  } else {
    stage(0, 0); stage(1, 1);
    kstart = 0;
  }

  // ---- per-gate phased K loop, counted vmcnt/lgkmcnt, never drain mid-loop ----
  for (int kt = kstart; kt < KT; ++kt){
    const int b = kt & 1;
    if (kt < KT - 1) asm volatile("s_waitcnt vmcnt(7)" ::: "memory");
    else             asm volatile("s_waitcnt vmcnt(0)" ::: "memory");
    SB0();
    __builtin_amdgcn_s_barrier();          // tile kt landed for all waves
    SB0();
    short8 af[2][4], b0[2][2], b1[2][2], b2[2][2];
    read_a(b, af);    SB0();               // 8 ds_reads
    read_b(b, 0, b0); SB0();               // 4
    read_b(b, 1, b1); SB0();               // 4
    asm volatile("s_waitcnt lgkmcnt(4)" ::: "memory"); SB0();   // af+b0 ready, b1 in flight
    __builtin_amdgcn_s_setprio(1);
    mfma_gate(af, b0, aR);
    __builtin_amdgcn_s_setprio(0);
    read_b(b, 2, b2); SB0();               // 4 (b1 may still be in flight)
    asm volatile("s_waitcnt lgkmcnt(4)" ::: "memory"); SB0();   // b1 ready, b2 in flight
    __builtin_amdgcn_s_setprio(1);
    mfma_gate(af, b1, aZ);
    __builtin_amdgcn_s_setprio(0);
    asm volatile("s_waitcnt lgkmcnt(0)" ::: "memory"); SB0();   // b2 ready
    __builtin_amdgcn_s_barrier();          // all waves' reads in regs -> buf free
    SB0();
    if (kt + 2 < KT) stage(b, kt + 2);     // overlaps with gate-N MFMA below
    __builtin_amdgcn_s_setprio(1);
    if (kt < NI_STEPS) mfma_gate(af, b2, aNI);
    else               mfma_gate(af, b2, aNH);
    __builtin_amdgcn_s_setprio(0);
  }

  // ---- epilogue: fused GRU nonlinearity + state update ----
  const int rq = (lane >> 4) * 4;
  #pragma unroll
  for (int fc = 0; fc < 2; ++fc){
    const int u = u0 + wn * 32 + fc * 16 + l15;
    const float br = a.bi[u] + a.bh[u];
    const float bz = a.bi[1024 + u] + a.bh[1024 + u];
    const float bni = a.bi[2048 + u];
    const float bnh = a.bh[2048 + u];
    #pragma unroll
    for (int fr = 0; fr < 4; ++fr){
      #pragma unroll
      for (int rg = 0; rg < 4; ++rg){
        const long row = brow + wm * 64 + fr * 16 + rq + rg;
        const float r = sigm(aR[fr][fc][rg] + br);
        const float z = sigm(aZ[fr][fc][rg] + bz);
        const float n = tanh_(aNI[fr][fc][rg] + bni + r * (aNH[fr][fc][rg] + bnh));
        const float hp = a.holdr[row * 1024 + u];
        const float hn = (1.f - z) * n + z * hp;
        a.holdw[row * 1024 + u] = hn;
        a.hbfw[row * 1024 + u] = f2bf(hn);
      }
    }
  }
}

// ---------------- out GEMM: out = h1n @ w_out.T + b_out  (M=2048,N=128,K=1024)
struct OutA { const u16* Ah; const u16* Wo; const float* bo; float* outf; };

__global__ __launch_bounds__(256, 2)
void out_kernel(OutA A0, OutA A1, const int* dn1, int step, float* __restrict__ dout, long outhalf){
  const int n1v = *dn1;
  if (step < n1v - 1) return;
  __shared__ u16 lA[2][32 * 64];
  __shared__ u16 lB[2][128 * 64];
  const OutA& a = (blockIdx.y == 0) ? A0 : A1;
  const int tid = threadIdx.x, lane = tid & 63, wv = tid >> 6;
  const int brow = blockIdx.x * 32;
  f32x4 acc[2][2] = {};
  const int srow = tid >> 3;
  const int sxor8 = ((tid & 7) ^ (srow & 7)) * 8;

  auto stage = [&](int bf, int kt){          // 5 gl_lds16 per thread
    const int k0 = kt * 64;
    gl_lds16(a.Ah + (long)(brow + srow) * 1024 + k0 + sxor8, &lA[bf][wv * 8 * 64]);
    #pragma unroll
    for (int j = 0; j < 4; ++j)
      gl_lds16(a.Wo + (long)(j * 32 + srow) * 1024 + k0 + sxor8,
               &lB[bf][(j * 32 + wv * 8) * 64]);
  };

  stage(0, 0); stage(1, 1);
  const int l15 = lane & 15, kq = lane >> 4, sx = lane & 7;
  for (int kt = 0; kt < 16; ++kt){
    const int b = kt & 1;
    if (kt < 15) asm volatile("s_waitcnt vmcnt(5)" ::: "memory");
    else         asm volatile("s_waitcnt vmcnt(0)" ::: "memory");
    SB0();
    __builtin_amdgcn_s_barrier();
    SB0();
    short8 af[2][2], bf2[2][2];
    #pragma unroll
    for (int ks = 0; ks < 2; ++ks){
      const int soff = (((ks * 4 + kq) ^ sx)) * 8;
      af[ks][0] = *(const short8*)&lA[b][(l15) * 64 + soff];
      af[ks][1] = *(const short8*)&lA[b][(16 + l15) * 64 + soff];
      bf2[ks][0] = *(const short8*)&lB[b][(wv * 32 + l15) * 64 + soff];
      bf2[ks][1] = *(const short8*)&lB[b][(wv * 32 + 16 + l15) * 64 + soff];
    }
    asm volatile("s_waitcnt lgkmcnt(0)" ::: "memory"); SB0();
    __builtin_amdgcn_s_barrier();
    SB0();
    if (kt + 2 < 16) stage(b, kt + 2);
    __builtin_amdgcn_s_setprio(1);
    #pragma unroll
    for (int ks = 0; ks < 2; ++ks)
      #pragma unroll
      for (int fr = 0; fr < 2; ++fr)
        #pragma unroll
        for (int fc = 0; fc < 2; ++fc)
          acc[fr][fc] = MFMA16(af[ks][fr], bf2[ks][fc], acc[fr][fc]);
    __builtin_amdgcn_s_setprio(0);
  }
  const int nst = 65 - n1v;
  const int t = step - (n1v - 1);
  const int rq = (lane >> 4) * 4;
  #pragma unroll
  for (int fc = 0; fc < 2; ++fc){
    const int u = wv * 32 + fc * 16 + l15;
    const float bo = a.bo[u];
    #pragma unroll
    for (int fr = 0; fr < 2; ++fr){
      #pragma unroll
      for (int rg = 0; rg < 4; ++rg){
        const long row = brow + fr * 16 + rq + rg;
        const float v = acc[fr][fc][rg] + bo;
        a.outf[row * 128 + u] = v;
        dout[(long)blockIdx.y * outhalf + (row * nst + t) * 128 + u] = v;
      }
    }
  }
}

// ---------------- host ----------------
extern "C" void kernel_launch(void* const* d_in, const int* in_sizes, int n_in,
                              void* d_out, int out_size, void* d_ws, size_t ws_size,
                              hipStream_t stream){
  // decoder 0 = z_p (output first): zp, zp8, cells 3&4, w_init1, w_out1
  // decoder 1 = z_r:                zr, zr8, cells 1&2, w_init0, w_out0
  const float* zz[2]   = { (const float*)d_in[0],  (const float*)d_in[1] };
  const float* z8[2]   = { (const float*)d_in[2],  (const float*)d_in[3] };
  const int* dn1       = (const int*)d_in[4];
  const float* wi_c1[2] = { (const float*)d_in[14], (const float*)d_in[6] };
  const float* wh_c1[2] = { (const float*)d_in[15], (const float*)d_in[7] };
  const float* bi_c1[2] = { (const float*)d_in[16], (const float*)d_in[8] };
  const float* bh_c1[2] = { (const float*)d_in[17], (const float*)d_in[9] };
  const float* wi_c2[2] = { (const float*)d_in[18], (const float*)d_in[10] };
  const float* wh_c2[2] = { (const float*)d_in[19], (const float*)d_in[11] };
  const float* bi_c2[2] = { (const float*)d_in[20], (const float*)d_in[12] };
  const float* bh_c2[2] = { (const float*)d_in[21], (const float*)d_in[13] };
  const float* wini[2]  = { (const float*)d_in[24], (const float*)d_in[22] };
  const float* bini[2]  = { (const float*)d_in[25], (const float*)d_in[23] };
  const float* wout[2]  = { (const float*)d_in[28], (const float*)d_in[26] };
  const float* bout[2]  = { (const float*)d_in[29], (const float*)d_in[27] };

  char* p = (char*)d_ws;
  auto alloc = [&](size_t bytes)->char*{
    char* q = p; p += (bytes + 255) & ~(size_t)255; return q;
  };
  u16* W1c[2]; u16* W2c[2]; u16* Woc[2];
  float* h0f[2]; float* h1f[2]; float* outf[2];
  u16* h0bf[2][2]; u16* h1bf[2][2];
  for (int d = 0; d < 2; ++d){
    W1c[d] = (u16*)alloc(3072ULL * 1152 * 2);
    W2c[d] = (u16*)alloc(3072ULL * 2048 * 2);
    Woc[d] = (u16*)alloc(128ULL * 1024 * 2);
    h0f[d] = (float*)alloc(2048ULL * 1024 * 4);
    h1f[d] = (float*)alloc(2048ULL * 1024 * 4);
    outf[d] = (float*)alloc(2048ULL * 128 * 4);
    for (int b = 0; b < 2; ++b){
      h0bf[d][b] = (u16*)alloc(2048ULL * 1024 * 2);
      h1bf[d][b] = (u16*)alloc(2048ULL * 1024 * 2);
    }
  }
  if ((size_t)(p - (char*)d_ws) > ws_size) return;

  for (int d = 0; d < 2; ++d){
    pack_w_kernel<<<dim3(1024), dim3(256), 0, stream>>>(wi_c1[d], wh_c1[d], W1c[d], 128, 1024, 3072);
    pack_w_kernel<<<dim3(1024), dim3(256), 0, stream>>>(wi_c2[d], wh_c2[d], W2c[d], 1024, 1024, 3072);
    pack_w_kernel<<<dim3(64),   dim3(256), 0, stream>>>(wout[d], wout[d], Woc[d], 1024, 0, 128);
  }
  {
    InitA I0{ z8[0], wini[0], bini[0], h0f[0], h0bf[0][0] };
    InitA I1{ z8[1], wini[1], bini[1], h0f[1], h0bf[1][0] };
    init_kernel<<<dim3(32, 8, 2), dim3(256), 0, stream>>>(I0, I1);
  }

  const long outhalf = (long)out_size / 2;

  for (int i = 0; i < 64; ++i){
    const int cur = i & 1, nxt = cur ^ 1;
    CellA c1[2], c2[2];
    for (int d = 0; d < 2; ++d){
      c1[d] = CellA{ W1c[d], bi_c1[d], bh_c1[d],
                     zz[d] + (long)i * 128, outf[d],
                     h0bf[d][cur], nullptr,
                     h0f[d], h0f[d], h0bf[d][nxt] };
      c2[d] = CellA{ W2c[d], bi_c2[d], bh_c2[d],
                     nullptr, nullptr,
                     h0bf[d][nxt], (i == 0) ? h0bf[d][nxt] : h1bf[d][cur],
                     (i == 0) ? h0f[d] : h1f[d], h1f[d], h1bf[d][nxt] };
    }
    cell_kernel<1><<<dim3(128, 2), dim3(512), 0, stream>>>(c1[0], c1[1], dn1, i);
    cell_kernel<2><<<dim3(128, 2), dim3(512), 0, stream>>>(c2[0], c2[1], dn1, i);
    OutA o0{ h1bf[0][nxt], Woc[0], bout[0], outf[0] };
    OutA o1{ h1bf[1][nxt], Woc[1], bout[1], outf[1] };
    out_kernel<<<dim3(64, 2), dim3(256), 0, stream>>>(o0, o1, dn1, i, (float*)d_out, outhalf);
  }
}

// Round 6
// 6628.129 us; speedup vs baseline: 1.0279x; 1.0279x over previous
//
#include <hip/hip_runtime.h>

typedef unsigned short u16;
typedef unsigned int u32;
typedef __attribute__((ext_vector_type(8))) short short8;
typedef __attribute__((ext_vector_type(4))) float f32x4;

#define DEV __device__ __forceinline__
#define SB0() __builtin_amdgcn_sched_barrier(0)

DEV u16 f2bf(float f){
  u32 u = __builtin_bit_cast(u32, f);
  u += 0x7fffu + ((u >> 16) & 1u);
  return (u16)(u >> 16);
}
DEV float sigm(float x){ return 1.f / (1.f + __expf(-x)); }
DEV float tanh_(float x){ return 2.f / (1.f + __expf(-2.f * x)) - 1.f; }

DEV void gl_lds16(const void* g, void* l){
  __builtin_amdgcn_global_load_lds(
      (const __attribute__((address_space(1))) u32*)g,
      (__attribute__((address_space(3))) u32*)l, 16, 0, 0);
}

#define MFMA16(A,B,C) __builtin_amdgcn_mfma_f32_16x16x32_bf16(A, B, C, 0, 0, 0)

// ---------------- weight pack ----------------
__global__ void pack_w_kernel(const float* __restrict__ wi, const float* __restrict__ wh,
                              u16* __restrict__ dst, int Ki, int Kh, int nrows){
  const int KT = Ki + Kh;
  const long n = (long)nrows * KT;
  for (long idx = (long)blockIdx.x * blockDim.x + threadIdx.x; idx < n;
       idx += (long)gridDim.x * blockDim.x){
    int r = (int)(idx / KT), c = (int)(idx % KT);
    float v = (c < Ki) ? wi[(long)r * Ki + c] : wh[(long)r * Kh + (c - Ki)];
    dst[idx] = f2bf(v);
  }
}

// ---------------- h0 init ----------------
struct InitA { const float* z8; const float* wini; const float* bini; float* h0f; u16* h0bf; };

__global__ __launch_bounds__(256)
void init_kernel(InitA A0, InitA A1){
  const InitA& a = (blockIdx.z == 0) ? A0 : A1;
  __shared__ float lz[64][128];
  const int tid = threadIdx.x;
  const int rb = blockIdx.x * 64, ub = blockIdx.y * 128;
  {
    const int row = tid >> 2, q = tid & 3;
    const float4* p = (const float4*)(a.z8 + (long)(rb + row) * 128 + q * 32);
    float4* dst = (float4*)&lz[row][q * 32];
    #pragma unroll
    for (int j = 0; j < 8; ++j) dst[j] = p[j];
  }
  __syncthreads();
  const int u = ub + (tid & 127);
  const int rg = tid >> 7;
  float acc[32];
  #pragma unroll
  for (int r = 0; r < 32; ++r) acc[r] = 0.f;
  for (int k = 0; k < 128; k += 4){
    float4 w4 = *(const float4*)&a.wini[(long)u * 128 + k];
    #pragma unroll
    for (int r = 0; r < 32; ++r){
      float4 z4 = *(const float4*)&lz[rg * 32 + r][k];
      acc[r] += w4.x * z4.x + w4.y * z4.y + w4.z * z4.z + w4.w * z4.w;
    }
  }
  const float b = a.bini[u];
  #pragma unroll
  for (int r = 0; r < 32; ++r){
    const long row = rb + rg * 32 + r;
    const float v = acc[r] + b;
    a.h0f[row * 1024 + u] = v;
    a.h0bf[row * 1024 + u] = f2bf(v);
  }
}

// ---------------- fused GRU cell GEMM (256x192 tile, monotone-read pipeline) ----
struct CellA {
  const u16* W;                 // [3072][KTOT] bf16 packed
  const float* bi; const float* bh;   // [3072]
  const float* afz; const float* afo; // cell1 f32 A region (z slice / prev out)
  const u16* ab1; const u16* ab2;     // bf16 A regions, row stride 1024
  const float* holdr; float* holdw; u16* hbfw;
};

template<int CELL>
__global__ __attribute__((amdgpu_waves_per_eu(2, 2))) __launch_bounds__(512)
void cell_kernel(CellA A0, CellA A1, const int* dn1, int step){
  constexpr int KTOT = (CELL == 1) ? 1152 : 2048;
  constexpr int KT = KTOT / 64;
  constexpr int NI_STEPS = (CELL == 1) ? 2 : 16;   // kt < NI_STEPS -> input-part of n-gate

  __shared__ u16 lA[2][256 * 64];
  __shared__ u16 lB[2][192 * 64];

  const CellA& a = (blockIdx.y == 0) ? A0 : A1;
  const int tid = threadIdx.x;
  const int lane = tid & 63;
  const int wv = tid >> 6;      // 0..7
  const int wm = wv >> 1;       // 0..3  (64-row group)
  const int wn = wv & 1;        // 0..1  (32-unit group)
  const int bid = blockIdx.x;
  // XCD supergroup swizzle: bid%8 selects (m-high, n-high); each XCD gets 4m x 4n
  const int inner = bid >> 3;                       // 0..15
  const int m_idx = ((bid >> 2) & 1) * 4 + (inner & 3);   // 0..7
  const int n_idx = (bid & 3) * 4 + (inner >> 2);         // 0..15
  const int brow = m_idx * 256;
  const int u0 = n_idx * 64;

  f32x4 aR[4][2] = {}; f32x4 aZ[4][2] = {};
  f32x4 aNI[4][2] = {}; f32x4 aNH[4][2] = {};

  const int srow = tid >> 3;                       // 0..63
  const int sxor8 = ((tid & 7) ^ (srow & 7)) * 8;  // pre-swizzled source slot (x8 u16)

  auto stage = [&](int bf, int kt){                // 7 gl_lds16 per thread per tile
    const int k0 = kt * 64;
    const u16* ab; int kk;
    if constexpr (CELL == 1){ ab = a.ab1; kk = k0 - 128; }
    else { if (k0 < 1024){ ab = a.ab1; kk = k0; } else { ab = a.ab2; kk = k0 - 1024; } }
    #pragma unroll
    for (int j = 0; j < 4; ++j)
      gl_lds16(ab + (long)(brow + j * 64 + srow) * 1024 + kk + sxor8,
               &lA[bf][(j * 64 + wv * 8) * 64]);
    #pragma unroll
    for (int g = 0; g < 3; ++g)
      gl_lds16(a.W + (long)(g * 1024 + u0 + srow) * KTOT + k0 + sxor8,
               &lB[bf][(g * 64 + wv * 8) * 64]);
  };

  const int l15 = lane & 15;
  const int kq = lane >> 4;
  const int sx = lane & 7;

  auto read_a = [&](int bf, short8 (&af)[2][4]){
    #pragma unroll
    for (int ks = 0; ks < 2; ++ks){
      const int soff = (((ks * 4 + kq) ^ sx)) * 8;
      #pragma unroll
      for (int fr = 0; fr < 4; ++fr)
        af[ks][fr] = *(const short8*)&lA[bf][(wm * 64 + fr * 16 + l15) * 64 + soff];
    }
  };
  auto read_b = [&](int bf, int g, short8 (&bg)[2][2]){
    #pragma unroll
    for (int ks = 0; ks < 2; ++ks){
      const int soff = (((ks * 4 + kq) ^ sx)) * 8;
      #pragma unroll
      for (int fc = 0; fc < 2; ++fc)
        bg[ks][fc] = *(const short8*)&lB[bf][(g * 64 + wn * 32 + fc * 16 + l15) * 64 + soff];
    }
  };
  auto mfma_gate = [&](const short8 (&af)[2][4], const short8 (&bg)[2][2], f32x4 (&A)[4][2]){
    #pragma unroll
    for (int ks = 0; ks < 2; ++ks)
      #pragma unroll
      for (int fr = 0; fr < 4; ++fr)
        #pragma unroll
        for (int fc = 0; fc < 2; ++fc)
          A[fr][fc] = MFMA16(af[ks][fr], bg[ks][fc], A[fr][fc]);
  };

  int kstart;
  if constexpr (CELL == 1){
    // ---- phase A: f32 input block (K=0..127), one-off ----
    const int n1v = *dn1;
    const float* fsrc; long fstr;
    if (step < n1v){ fsrc = a.afz; fstr = 64 * 128; }
    else           { fsrc = a.afo; fstr = 128; }
    {
      const int row = tid >> 1, half = tid & 1;
      #pragma unroll
      for (int st = 0; st < 2; ++st){
        const float* pp = fsrc + (long)(brow + row) * fstr + st * 64 + half * 32;
        #pragma unroll
        for (int q = 0; q < 4; ++q){
          float4 x = ((const float4*)pp)[2 * q];
          float4 y = ((const float4*)pp)[2 * q + 1];
          short8 o;
          o[0] = (short)f2bf(x.x); o[1] = (short)f2bf(x.y);
          o[2] = (short)f2bf(x.z); o[3] = (short)f2bf(x.w);
          o[4] = (short)f2bf(y.x); o[5] = (short)f2bf(y.y);
          o[6] = (short)f2bf(y.z); o[7] = (short)f2bf(y.w);
          const int s = half * 4 + q;
          *(short8*)&lA[st][row * 64 + ((s ^ (row & 7)) * 8)] = o;
        }
        #pragma unroll
        for (int g = 0; g < 3; ++g)
          gl_lds16(a.W + (long)(g * 1024 + u0 + srow) * KTOT + st * 64 + sxor8,
                   &lB[st][(g * 64 + wv * 8) * 64]);
      }
    }
    __syncthreads();                       // full drain ok (one-time)
    #pragma unroll
    for (int st = 0; st < 2; ++st){
      short8 af[2][4], b0[2][2], b1[2][2], b2[2][2];
      read_a(st, af);    SB0();
      read_b(st, 0, b0); SB0();
      read_b(st, 1, b1); SB0();
      read_b(st, 2, b2); SB0();
      asm volatile("s_waitcnt lgkmcnt(8)" ::: "memory"); SB0();
      mfma_gate(af, b0, aR);
      asm volatile("s_waitcnt lgkmcnt(4)" ::: "memory"); SB0();
      mfma_gate(af, b1, aZ);
      asm volatile("s_waitcnt lgkmcnt(0)" ::: "memory"); SB0();
      mfma_gate(af, b2, aNI);
    }
    __syncthreads();                       // all reads done -> buffers free
    stage(0, 2); stage(1, 3);
    kstart = 2;
  } else {
    stage(0, 0); stage(1, 1);
    kstart = 0;
  }

  // ---- monotone-read K loop: all 20 ds_reads queued up front, counted lgkm ----
  for (int kt = kstart; kt < KT; ++kt){
    const int b = kt & 1;
    if (kt < KT - 1) asm volatile("s_waitcnt vmcnt(7)" ::: "memory");
    else             asm volatile("s_waitcnt vmcnt(0)" ::: "memory");
    SB0();
    __builtin_amdgcn_s_barrier();          // buf b staged for all waves
    SB0();
    short8 af[2][4], b0[2][2], b1[2][2], b2[2][2];
    read_a(b, af);    SB0();               // 8 ds_reads  (FIFO group 1)
    read_b(b, 0, b0); SB0();               // 4           (group 2)
    read_b(b, 1, b1); SB0();               // 4           (group 3)
    read_b(b, 2, b2); SB0();               // 4           (group 4)
    asm volatile("s_waitcnt lgkmcnt(8)" ::: "memory"); SB0();   // af+b0 ready; b1,b2 streaming
    __builtin_amdgcn_s_setprio(1);
    mfma_gate(af, b0, aR);
    __builtin_amdgcn_s_setprio(0);
    asm volatile("s_waitcnt lgkmcnt(4)" ::: "memory"); SB0();   // b1 ready; b2 streaming
    __builtin_amdgcn_s_setprio(1);
    mfma_gate(af, b1, aZ);
    __builtin_amdgcn_s_setprio(0);
    asm volatile("s_waitcnt lgkmcnt(0)" ::: "memory"); SB0();   // all reads in regs
    __builtin_amdgcn_s_barrier();          // -> buf b free for staging
    SB0();
    if (kt + 2 < KT) stage(b, kt + 2);     // overlaps gate-N MFMA
    __builtin_amdgcn_s_setprio(1);
    if (kt < NI_STEPS) mfma_gate(af, b2, aNI);
    else               mfma_gate(af, b2, aNH);
    __builtin_amdgcn_s_setprio(0);
  }

  // ---- epilogue: fused GRU nonlinearity + state update ----
  const int rq = (lane >> 4) * 4;
  #pragma unroll
  for (int fc = 0; fc < 2; ++fc){
    const int u = u0 + wn * 32 + fc * 16 + l15;
    const float br = a.bi[u] + a.bh[u];
    const float bz = a.bi[1024 + u] + a.bh[1024 + u];
    const float bni = a.bi[2048 + u];
    const float bnh = a.bh[2048 + u];
    #pragma unroll
    for (int fr = 0; fr < 4; ++fr){
      #pragma unroll
      for (int rg = 0; rg < 4; ++rg){
        const long row = brow + wm * 64 + fr * 16 + rq + rg;
        const float r = sigm(aR[fr][fc][rg] + br);
        const float z = sigm(aZ[fr][fc][rg] + bz);
        const float n = tanh_(aNI[fr][fc][rg] + bni + r * (aNH[fr][fc][rg] + bnh));
        const float hp = a.holdr[row * 1024 + u];
        const float hn = (1.f - z) * n + z * hp;
        a.holdw[row * 1024 + u] = hn;
        a.hbfw[row * 1024 + u] = f2bf(hn);
      }
    }
  }
}

// ---------------- out GEMM: out = h1n @ w_out.T + b_out  (M=2048,N=128,K=1024)
struct OutA { const u16* Ah; const u16* Wo; const float* bo; float* outf; };

__global__ __launch_bounds__(256, 2)
void out_kernel(OutA A0, OutA A1, const int* dn1, int step, float* __restrict__ dout, long outhalf){
  const int n1v = *dn1;
  if (step < n1v - 1) return;
  __shared__ u16 lA[2][32 * 64];
  __shared__ u16 lB[2][128 * 64];
  const OutA& a = (blockIdx.y == 0) ? A0 : A1;
  const int tid = threadIdx.x, lane = tid & 63, wv = tid >> 6;
  const int brow = blockIdx.x * 32;
  f32x4 acc[2][2] = {};
  const int srow = tid >> 3;
  const int sxor8 = ((tid & 7) ^ (srow & 7)) * 8;

  auto stage = [&](int bf, int kt){          // 5 gl_lds16 per thread
    const int k0 = kt * 64;
    gl_lds16(a.Ah + (long)(brow + srow) * 1024 + k0 + sxor8, &lA[bf][wv * 8 * 64]);
    #pragma unroll
    for (int j = 0; j < 4; ++j)
      gl_lds16(a.Wo + (long)(j * 32 + srow) * 1024 + k0 + sxor8,
               &lB[bf][(j * 32 + wv * 8) * 64]);
  };

  stage(0, 0); stage(1, 1);
  const int l15 = lane & 15, kq = lane >> 4, sx = lane & 7;
  for (int kt = 0; kt < 16; ++kt){
    const int b = kt & 1;
    if (kt < 15) asm volatile("s_waitcnt vmcnt(5)" ::: "memory");
    else         asm volatile("s_waitcnt vmcnt(0)" ::: "memory");
    SB0();
    __builtin_amdgcn_s_barrier();
    SB0();
    short8 af[2][2], bf2[2][2];
    #pragma unroll
    for (int ks = 0; ks < 2; ++ks){
      const int soff = (((ks * 4 + kq) ^ sx)) * 8;
      af[ks][0] = *(const short8*)&lA[b][(l15) * 64 + soff];
      af[ks][1] = *(const short8*)&lA[b][(16 + l15) * 64 + soff];
      bf2[ks][0] = *(const short8*)&lB[b][(wv * 32 + l15) * 64 + soff];
      bf2[ks][1] = *(const short8*)&lB[b][(wv * 32 + 16 + l15) * 64 + soff];
    }
    asm volatile("s_waitcnt lgkmcnt(0)" ::: "memory"); SB0();
    __builtin_amdgcn_s_barrier();
    SB0();
    if (kt + 2 < 16) stage(b, kt + 2);
    __builtin_amdgcn_s_setprio(1);
    #pragma unroll
    for (int ks = 0; ks < 2; ++ks)
      #pragma unroll
      for (int fr = 0; fr < 2; ++fr)
        #pragma unroll
        for (int fc = 0; fc < 2; ++fc)
          acc[fr][fc] = MFMA16(af[ks][fr], bf2[ks][fc], acc[fr][fc]);
    __builtin_amdgcn_s_setprio(0);
  }
  const int nst = 65 - n1v;
  const int t = step - (n1v - 1);
  const int rq = (lane >> 4) * 4;
  #pragma unroll
  for (int fc = 0; fc < 2; ++fc){
    const int u = wv * 32 + fc * 16 + l15;
    const float bo = a.bo[u];
    #pragma unroll
    for (int fr = 0; fr < 2; ++fr){
      #pragma unroll
      for (int rg = 0; rg < 4; ++rg){
        const long row = brow + fr * 16 + rq + rg;
        const float v = acc[fr][fc][rg] + bo;
        a.outf[row * 128 + u] = v;
        dout[(long)blockIdx.y * outhalf + (row * nst + t) * 128 + u] = v;
      }
    }
  }
}

// ---------------- host ----------------
extern "C" void kernel_launch(void* const* d_in, const int* in_sizes, int n_in,
                              void* d_out, int out_size, void* d_ws, size_t ws_size,
                              hipStream_t stream){
  // decoder 0 = z_p (output first): zp, zp8, cells 3&4, w_init1, w_out1
  // decoder 1 = z_r:                zr, zr8, cells 1&2, w_init0, w_out0
  const float* zz[2]   = { (const float*)d_in[0],  (const float*)d_in[1] };
  const float* z8[2]   = { (const float*)d_in[2],  (const float*)d_in[3] };
  const int* dn1       = (const int*)d_in[4];
  const float* wi_c1[2] = { (const float*)d_in[14], (const float*)d_in[6] };
  const float* wh_c1[2] = { (const float*)d_in[15], (const float*)d_in[7] };
  const float* bi_c1[2] = { (const float*)d_in[16], (const float*)d_in[8] };
  const float* bh_c1[2] = { (const float*)d_in[17], (const float*)d_in[9] };
  const float* wi_c2[2] = { (const float*)d_in[18], (const float*)d_in[10] };
  const float* wh_c2[2] = { (const float*)d_in[19], (const float*)d_in[11] };
  const float* bi_c2[2] = { (const float*)d_in[20], (const float*)d_in[12] };
  const float* bh_c2[2] = { (const float*)d_in[21], (const float*)d_in[13] };
  const float* wini[2]  = { (const float*)d_in[24], (const float*)d_in[22] };
  const float* bini[2]  = { (const float*)d_in[25], (const float*)d_in[23] };
  const float* wout[2]  = { (const float*)d_in[28], (const float*)d_in[26] };
  const float* bout[2]  = { (const float*)d_in[29], (const float*)d_in[27] };

  char* p = (char*)d_ws;
  auto alloc = [&](size_t bytes)->char*{
    char* q = p; p += (bytes + 255) & ~(size_t)255; return q;
  };
  u16* W1c[2]; u16* W2c[2]; u16* Woc[2];
  float* h0f[2]; float* h1f[2]; float* outf[2];
  u16* h0bf[2][2]; u16* h1bf[2][2];
  for (int d = 0; d < 2; ++d){
    W1c[d] = (u16*)alloc(3072ULL * 1152 * 2);
    W2c[d] = (u16*)alloc(3072ULL * 2048 * 2);
    Woc[d] = (u16*)alloc(128ULL * 1024 * 2);
    h0f[d] = (float*)alloc(2048ULL * 1024 * 4);
    h1f[d] = (float*)alloc(2048ULL * 1024 * 4);
    outf[d] = (float*)alloc(2048ULL * 128 * 4);
    for (int b = 0; b < 2; ++b){
      h0bf[d][b] = (u16*)alloc(2048ULL * 1024 * 2);
      h1bf[d][b] = (u16*)alloc(2048ULL * 1024 * 2);
    }
  }
  if ((size_t)(p - (char*)d_ws) > ws_size) return;

  for (int d = 0; d < 2; ++d){
    pack_w_kernel<<<dim3(1024), dim3(256), 0, stream>>>(wi_c1[d], wh_c1[d], W1c[d], 128, 1024, 3072);
    pack_w_kernel<<<dim3(1024), dim3(256), 0, stream>>>(wi_c2[d], wh_c2[d], W2c[d], 1024, 1024, 3072);
    pack_w_kernel<<<dim3(64),   dim3(256), 0, stream>>>(wout[d], wout[d], Woc[d], 1024, 0, 128);
  }
  {
    InitA I0{ z8[0], wini[0], bini[0], h0f[0], h0bf[0][0] };
    InitA I1{ z8[1], wini[1], bini[1], h0f[1], h0bf[1][0] };
    init_kernel<<<dim3(32, 8, 2), dim3(256), 0, stream>>>(I0, I1);
  }

  const long outhalf = (long)out_size / 2;

  for (int i = 0; i < 64; ++i){
    const int cur = i & 1, nxt = cur ^ 1;
    CellA c1[2], c2[2];
    for (int d = 0; d < 2; ++d){
      c1[d] = CellA{ W1c[d], bi_c1[d], bh_c1[d],
                     zz[d] + (long)i * 128, outf[d],
                     h0bf[d][cur], nullptr,
                     h0f[d], h0f[d], h0bf[d][nxt] };
      c2[d] = CellA{ W2c[d], bi_c2[d], bh_c2[d],
                     nullptr, nullptr,
                     h0bf[d][nxt], (i == 0) ? h0bf[d][nxt] : h1bf[d][cur],
                     (i == 0) ? h0f[d] : h1f[d], h1f[d], h1bf[d][nxt] };
    }
    cell_kernel<1><<<dim3(128, 2), dim3(512), 0, stream>>>(c1[0], c1[1], dn1, i);
    cell_kernel<2><<<dim3(128, 2), dim3(512), 0, stream>>>(c2[0], c2[1], dn1, i);
    OutA o0{ h1bf[0][nxt], Woc[0], bout[0], outf[0] };
    OutA o1{ h1bf[1][nxt], Woc[1], bout[1], outf[1] };
    out_kernel<<<dim3(64, 2), dim3(256), 0, stream>>>(o0, o1, dn1, i, (float*)d_out, outhalf);
  }
}